// Round 16
// baseline (81.837 us; speedup 1.0000x reference)
//
#include <hip/hip_runtime.h>

// DCN-v2 low-rank mixture, L=3 E=4 D=512 R=64 B=16384.
// gate = softmax over size-1 axis == 1  -> G unused.
// xl' = x0 * (sum_e U_e tanh(C_e tanh(V_e^T xl)) + 4*bias) + xl, rows independent.
// R16: = R15 (global_load_lds weight ring, counted vmcnt) + the missing
//      WAR fence: s_waitcnt lgkmcnt(0) BEFORE each gll16 issue, so the slot's
//      previous ds_read is complete before the DMA can overwrite it
//      (ds_read/lgkmcnt and global_load_lds/vmcnt are not mutually ordered).
//      Ring: wave-private 4 slots x 1KB, depth 4 in flight.
//      LDS = 64K xl + 32K sbuf + 64K ring = 160 KiB. x0 in 16 packed VGPRs.

#define NL 3
#define NE 4
#define DD 512
#define RR 64
#define ROWS 64    // rows per block; grid = 16384/64 = 256 blocks
#define THREADS 1024

typedef __attribute__((ext_vector_type(8))) _Float16 f16x8;   // 8 fp16 = 4 VGPR
typedef __attribute__((ext_vector_type(4))) float f32x4;

#define MFMA(a, b, c) __builtin_amdgcn_mfma_f32_16x16x32_f16((a), (b), (c), 0, 0, 0)

__device__ __forceinline__ short f16b(float f) {
    _Float16 h = (_Float16)f;
    return __builtin_bit_cast(short, h);
}
__device__ __forceinline__ float f16tof(short s) {
    return (float)__builtin_bit_cast(_Float16, s);
}

__device__ __forceinline__ float ftanh(float x) {
    float t = __builtin_amdgcn_exp2f(x * 2.8853900817779268f);
    return 1.0f - 2.0f * __builtin_amdgcn_rcpf(t + 1.0f);
}

// async global->LDS: one call stages 64 lanes x 16B = 1KB fragment.
// LDS dest = wave-uniform base + lane*16 (linear); global src is per-lane.
__device__ __forceinline__ void gll16(const short* g, char* l) {
    __builtin_amdgcn_global_load_lds(
        (const __attribute__((address_space(1))) unsigned int*)g,
        (__attribute__((address_space(3))) unsigned int*)l, 16, 0, 0);
}

// counted vmcnt wait; n is unroll-constant -> folds to one s_waitcnt
__device__ __forceinline__ void vwait(int n) {
    if (n <= 0)      asm volatile("s_waitcnt vmcnt(0)" ::: "memory");
    else if (n == 1) asm volatile("s_waitcnt vmcnt(1)" ::: "memory");
    else if (n == 2) asm volatile("s_waitcnt vmcnt(2)" ::: "memory");
    else             asm volatile("s_waitcnt vmcnt(3)" ::: "memory");
}
// WAR fence: all prior ds_reads complete before the next DMA write can land
__device__ __forceinline__ void lgkm0() {
    asm volatile("s_waitcnt lgkmcnt(0)" ::: "memory");
}

// ---- prep: fp16-cast + permute weights into MFMA-fragment-contiguous order ----
// Fragment element (lane ln, j): col = 16*colblk + (ln&15), k = 32*kstep + (ln>>4)*8 + j.
// Vb2[l][colblk(16)][ks(16)][ln(64)][j(8)]  = V[l][e=colblk>>2][d=32ks+8(ln>>4)+j][r=16(colblk&3)+(ln&15)]
// Ub2[l][dblk(32)][ks(8)][ln][j]            = U[l][e=ks>>1][d=16dblk+(ln&15)][s=32(ks&1)+8(ln>>4)+j]
// Ct2[l][e(4)][oc(4)][kc(2)][ln][j]         = C[l][e][r=32kc+8(ln>>4)+j][s=16oc+(ln&15)]
__global__ void prep_kernel(const float* __restrict__ U, const float* __restrict__ V,
                            const float* __restrict__ C,
                            short* __restrict__ Vb2, short* __restrict__ Ub2,
                            short* __restrict__ Ct2)
{
    int tid  = blockIdx.x * 256 + threadIdx.x;
    int nthr = gridDim.x * 256;
    for (int i = tid; i < NL * 131072; i += nthr) {
        int l = i >> 17; int q = i & 131071;
        int colblk = q >> 13; int rem = q & 8191;
        int ks = rem >> 9; int ln = (rem >> 3) & 63; int j = rem & 7;
        int e = colblk >> 2;
        int r = (colblk & 3) * 16 + (ln & 15);
        int d = ks * 32 + (ln >> 4) * 8 + j;
        Vb2[i] = f16b(V[(((size_t)l * NE + e) * DD + d) * RR + r]);
    }
    for (int i = tid; i < NL * 131072; i += nthr) {
        int l = i >> 17; int q = i & 131071;
        int dblk = q >> 12; int rem = q & 4095;
        int ks = rem >> 9; int ln = (rem >> 3) & 63; int j = rem & 7;
        int e = ks >> 1;
        int d = dblk * 16 + (ln & 15);
        int s = (ks & 1) * 32 + (ln >> 4) * 8 + j;
        Ub2[i] = f16b(U[(((size_t)l * NE + e) * DD + d) * RR + s]);
    }
    for (int i = tid; i < NL * 16384; i += nthr) {
        int l = i >> 14; int q = i & 16383;
        int e = q >> 12; int rem = q & 4095;
        int oc = rem >> 10; int kc = (rem >> 9) & 1;
        int ln = (rem >> 3) & 63; int j = rem & 7;
        int r = kc * 32 + (ln >> 4) * 8 + j;
        int s = oc * 16 + (ln & 15);
        Ct2[i] = f16b(C[(((size_t)l * NE + e) * RR + r) * RR + s]);
    }
}

// 16-slot XOR swizzle (R14-proven conflict-free for these access patterns)
#define XLB_ADDR(row, colbyte) (((row) * (DD * 2)) + ((colbyte) ^ (((row) & 15) << 4)))
#define VB_ADDR(row, colbyte)  (((row) * (NE * RR * 2)) + ((colbyte) ^ (((row) & 15) << 4)))

__global__ __launch_bounds__(THREADS, 4) void dcn_main(
    const float* __restrict__ x,
    const float* __restrict__ bias,
    const short* __restrict__ Vb2,
    const short* __restrict__ Ub2,
    const short* __restrict__ Ct2,
    float* __restrict__ out)
{
    __shared__ char xl_b[ROWS * DD * 2];        // 64 KiB fp16 xl carry tile (swizzled)
    __shared__ char sbuf[ROWS * NE * RR * 2];   // 32 KiB shared v/cv tile (swizzled)
    __shared__ char wring[16 * 4096];           // 64 KiB: per-wave 4-slot weight ring

    const int t   = threadIdx.x;
    const int w   = t >> 6;          // wave 0..15
    const int ln  = t & 63;
    const int l15 = ln & 15;
    const int kg  = ln >> 4;         // k-group 0..3
    const int row_base = blockIdx.x * ROWS;
    char* wsb = wring + w * 4096;    // this wave's private ring

    // ---- preamble: x (fp32, coalesced float4) -> fp16 xl_b ----
    #pragma unroll
    for (int q = 0; q < 8; ++q) {
        int p   = t + q * THREADS;
        int row = p >> 7;                 // 128 float4 per row
        int d4  = (p & 127) << 2;
        const float4 v4 = *(const float4*)(x + (size_t)(row_base + row) * DD + d4);
        short4 pk;
        pk.x = f16b(v4.x); pk.y = f16b(v4.y); pk.z = f16b(v4.z); pk.w = f16b(v4.w);
        *(short4*)(xl_b + XLB_ADDR(row, d4 * 2)) = pk;
    }
    __syncthreads();

    const int e2 = w >> 2;           // GEMM2 expert (4 waves/expert)
    const int q2 = w & 3;            // GEMM2 16-col quarter within expert

    unsigned x0p[2][4][2];           // x0 packed fp16x2, captured in layer-0 epilogue

    #pragma unroll
    for (int layer = 0; layer < NL; ++layer) {
        const short* Vl = Vb2 + layer * 131072;
        const short* Ul = Ub2 + layer * 131072;
        const short* Cl = Ct2 + layer * 16384;
        const float* bl = bias + layer * DD;

        // ---- GEMM1: v = tanh(xl @ V); wave owns v-cols [w*16, w*16+16) ----
        // 16-step global_load_lds pipeline, depth 4, counted vmcnt, WAR-fenced.
        const short* Vw = Vl + ((w * 16) << 9);   // wave's 16 contiguous 1KB frags
        f32x4 acc1[4];
        #pragma unroll
        for (int mt = 0; mt < 4; ++mt) { f32x4 z = {0.f, 0.f, 0.f, 0.f}; acc1[mt] = z; }

        lgkm0();   // cross-phase pending LDS reads done before DMA can land
        #pragma unroll
        for (int p = 0; p < 3; ++p)
            gll16(Vw + (p << 9) + ln * 8, wsb + (p << 10));
        #pragma unroll
        for (int ks = 0; ks < 16; ++ks) {
            lgkm0();                      // slot (ks+3)&3's previous read complete
            if (ks + 3 < 16)
                gll16(Vw + ((ks + 3) << 9) + ln * 8, wsb + (((ks + 3) & 3) << 10));
            vwait(15 - ks >= 3 ? 3 : 15 - ks);   // load ks landed
            f16x8 b = *(const f16x8*)(wsb + ((ks & 3) << 10) + ln * 16);
            const int d0 = ks * 32 + kg * 8;
            #pragma unroll
            for (int mt = 0; mt < 4; ++mt) {
                f16x8 a = *(const f16x8*)(xl_b + XLB_ADDR(l15 + 16 * mt, d0 * 2));
                acc1[mt] = MFMA(a, b, acc1[mt]);
            }
        }
        #pragma unroll
        for (int mt = 0; mt < 4; ++mt)
          #pragma unroll
          for (int r = 0; r < 4; ++r) {
              int row = mt * 16 + kg * 4 + r;
              int col = w * 16 + l15;
              *(short*)(sbuf + VB_ADDR(row, col * 2)) = f16b(ftanh(acc1[mt][r]));
          }
        // GEMM2's tiny C b-frags: plain loads (pipeline drained, vmcnt clean)
        f16x8 pfc0 = *(const f16x8*)(Cl + ((e2 * 8 + q2 * 2 + 0) << 9) + ln * 8);
        f16x8 pfc1 = *(const f16x8*)(Cl + ((e2 * 8 + q2 * 2 + 1) << 9) + ln * 8);
        __syncthreads();   // v visible

        // ---- GEMM2: cv = tanh(v @ C_e); 4 waves per expert, 16 cols each ----
        f32x4 acc2[4];
        #pragma unroll
        for (int mt = 0; mt < 4; ++mt) { f32x4 z = {0.f, 0.f, 0.f, 0.f}; acc2[mt] = z; }

        #pragma unroll
        for (int kc = 0; kc < 2; ++kc) {
            const int vcol = e2 * 64 + kc * 32 + kg * 8;
            f16x8 b = kc ? pfc1 : pfc0;
            #pragma unroll
            for (int mt = 0; mt < 4; ++mt) {
                f16x8 a = *(const f16x8*)(sbuf + VB_ADDR(l15 + 16 * mt, vcol * 2));
                acc2[mt] = MFMA(a, b, acc2[mt]);
            }
        }
        float cvv[4][4];
        #pragma unroll
        for (int mt = 0; mt < 4; ++mt)
          #pragma unroll
          for (int r = 0; r < 4; ++r) cvv[mt][r] = ftanh(acc2[mt][r]);
        __syncthreads();   // all v-reads done before cv overwrites sbuf
        #pragma unroll
        for (int mt = 0; mt < 4; ++mt)
          #pragma unroll
          for (int r = 0; r < 4; ++r) {
              int row = mt * 16 + kg * 4 + r;
              int col = e2 * 64 + q2 * 16 + l15;
              *(short*)(sbuf + VB_ADDR(row, col * 2)) = f16b(cvv[mt][r]);
          }
        __syncthreads();   // cv visible

        // ---- GEMM3 in two nt-halves, 8-step fenced gll pipeline, fused epilogue ----
        #pragma unroll
        for (int h = 0; h < 2; ++h) {
            const short* Uw = Ul + (((w * 2 + h) * 8) << 9);
            f32x4 acc3[4];
            #pragma unroll
            for (int mt = 0; mt < 4; ++mt) { f32x4 z = {0.f, 0.f, 0.f, 0.f}; acc3[mt] = z; }

            lgkm0();
            #pragma unroll
            for (int p = 0; p < 3; ++p)
                gll16(Uw + (p << 9) + ln * 8, wsb + (p << 10));
            #pragma unroll
            for (int ks = 0; ks < 8; ++ks) {
                lgkm0();                  // slot (ks+3)&3's previous read complete
                if (ks + 3 < 8)
                    gll16(Uw + ((ks + 3) << 9) + ln * 8, wsb + (((ks + 3) & 3) << 10));
                vwait(7 - ks >= 3 ? 3 : 7 - ks);
                f16x8 b = *(const f16x8*)(wsb + ((ks & 3) << 10) + ln * 16);
                const int k0 = ks * 32 + kg * 8;
                #pragma unroll
                for (int mt = 0; mt < 4; ++mt) {
                    f16x8 a = *(const f16x8*)(sbuf + VB_ADDR(l15 + 16 * mt, k0 * 2));
                    acc3[mt] = MFMA(a, b, acc3[mt]);
                }
            }

            // epilogue for this half (pure LDS): xl' = x0*(ucv + 4*bias) + xl_old
            const int col = w * 32 + h * 16 + l15;
            const float bv = 4.0f * bl[col];
            #pragma unroll
            for (int mt = 0; mt < 4; ++mt) {
                const int row0 = mt * 16 + kg * 4;
                #pragma unroll
                for (int pr = 0; pr < 2; ++pr) {
                    short h0 = *(const short*)(xl_b + XLB_ADDR(row0 + pr * 2 + 0, col * 2));
                    short h1 = *(const short*)(xl_b + XLB_ADDR(row0 + pr * 2 + 1, col * 2));
                    float xo0 = f16tof(h0), xo1 = f16tof(h1);
                    float x00, x01;
                    if (layer == 0) {
                        x00 = xo0; x01 = xo1;
                        x0p[h][mt][pr] = (unsigned)(unsigned short)h0
                                       | ((unsigned)(unsigned short)h1 << 16);
                    } else {
                        unsigned pk = x0p[h][mt][pr];
                        x00 = f16tof((short)(pk & 0xffffu));
                        x01 = f16tof((short)(pk >> 16));
                    }
                    float n0 = x00 * (acc3[mt][pr * 2 + 0] + bv) + xo0;
                    float n1 = x01 * (acc3[mt][pr * 2 + 1] + bv) + xo1;
                    *(short*)(xl_b + XLB_ADDR(row0 + pr * 2 + 0, col * 2)) = f16b(n0);
                    *(short*)(xl_b + XLB_ADDR(row0 + pr * 2 + 1, col * 2)) = f16b(n1);
                }
            }
        }
        __syncthreads();   // xl' visible to next GEMM1 / final copy
    }

    // ---- final: coalesced float4 store of xl_b (fp16 -> fp32) ----
    #pragma unroll
    for (int q = 0; q < 8; ++q) {
        int p   = t + q * THREADS;
        int row = p >> 7;
        int d4  = (p & 127) << 2;
        short4 pk = *(const short4*)(xl_b + XLB_ADDR(row, d4 * 2));
        float4 v4;
        v4.x = f16tof(pk.x); v4.y = f16tof(pk.y); v4.z = f16tof(pk.z); v4.w = f16tof(pk.w);
        *(float4*)(out + (size_t)(row_base + row) * DD + d4) = v4;
    }
}

extern "C" void kernel_launch(void* const* d_in, const int* in_sizes, int n_in,
                              void* d_out, int out_size, void* d_ws, size_t ws_size,
                              hipStream_t stream) {
    const float* x    = (const float*)d_in[0];
    const float* U    = (const float*)d_in[1];
    const float* V    = (const float*)d_in[2];
    const float* C    = (const float*)d_in[3];
    // d_in[4] = G : unused (gate == 1 exactly)
    const float* bias = (const float*)d_in[5];
    float* out = (float*)d_out;

    short* Vb2 = (short*)d_ws;                 // 786432 B
    short* Ub2 = Vb2 + NL * 131072;            // 786432 B
    short* Ct2 = Ub2 + NL * 131072;            // 98304 B  (total ~1.6 MiB)

    prep_kernel<<<dim3(256), dim3(256), 0, stream>>>(U, V, C, Vb2, Ub2, Ct2);
    dcn_main<<<dim3(16384 / ROWS), dim3(THREADS), 0, stream>>>(x, bias, Vb2, Ub2, Ct2, out);
}

// Round 17
// 53.627 us; speedup vs baseline: 1.5261x; 1.5261x over previous
//
#include <hip/hip_runtime.h>

// DCN-v2 low-rank mixture, L=3 E=4 D=512 R=64 B=16384.
// gate = softmax over size-1 axis == 1  -> G unused.
// xl' = x0 * (sum_e U_e tanh(C_e tanh(V_e^T xl)) + 4*bias) + xl, rows independent.
// R17: = R13 structure (plain unroll-4 weight loads, x0 in LDS, grid 256,
//      1024 thr, 160KB LDS) with SWAPPED MFMA operands in all three GEMMs:
//      D^T = W^T * Act^T. A-operand = weight fragment (same layouts), B-operand
//      = activation b128 reads (same addresses). Output lanes now hold 4
//      CONSECUTIVE weight-columns per batch row -> all v/cv/epilogue LDS ops
//      become vectorized b64 (short4): 128 scalar ops/wave/layer -> 32 b64.

#define NL 3
#define NE 4
#define DD 512
#define RR 64
#define ROWS 64    // rows per block; grid = 16384/64 = 256 blocks
#define THREADS 1024

typedef __attribute__((ext_vector_type(8))) _Float16 f16x8;   // 8 fp16 = 4 VGPR
typedef __attribute__((ext_vector_type(4))) float f32x4;

#define MFMA(a, b, c) __builtin_amdgcn_mfma_f32_16x16x32_f16((a), (b), (c), 0, 0, 0)

__device__ __forceinline__ short f16b(float f) {
    _Float16 h = (_Float16)f;
    return __builtin_bit_cast(short, h);
}
__device__ __forceinline__ float f16tof(short s) {
    return (float)__builtin_bit_cast(_Float16, s);
}

__device__ __forceinline__ float ftanh(float x) {
    float t = __builtin_amdgcn_exp2f(x * 2.8853900817779268f);
    return 1.0f - 2.0f * __builtin_amdgcn_rcpf(t + 1.0f);
}

// ---- prep: fp16-cast + permute weights into MFMA-fragment-contiguous order ----
// Fragment element (lane ln, j): idx = 16*blk + (ln&15), k = 32*kstep + (ln>>4)*8 + j.
// (A- and B-operand lane mappings are identical for mfma_16x16x32_f16, so these
//  fragments serve as A-operands in the swapped GEMMs unchanged.)
// Vb2[l][colblk(16)][ks(16)][ln(64)][j(8)]  = V[l][e=colblk>>2][d=32ks+8(ln>>4)+j][r=16(colblk&3)+(ln&15)]
// Ub2[l][dblk(32)][ks(8)][ln][j]            = U[l][e=ks>>1][d=16dblk+(ln&15)][s=32(ks&1)+8(ln>>4)+j]
// Ct2[l][e(4)][oc(4)][kc(2)][ln][j]         = C[l][e][r=32kc+8(ln>>4)+j][s=16oc+(ln&15)]
__global__ void prep_kernel(const float* __restrict__ U, const float* __restrict__ V,
                            const float* __restrict__ C,
                            short* __restrict__ Vb2, short* __restrict__ Ub2,
                            short* __restrict__ Ct2)
{
    int tid  = blockIdx.x * 256 + threadIdx.x;
    int nthr = gridDim.x * 256;
    for (int i = tid; i < NL * 131072; i += nthr) {
        int l = i >> 17; int q = i & 131071;
        int colblk = q >> 13; int rem = q & 8191;
        int ks = rem >> 9; int ln = (rem >> 3) & 63; int j = rem & 7;
        int e = colblk >> 2;
        int r = (colblk & 3) * 16 + (ln & 15);
        int d = ks * 32 + (ln >> 4) * 8 + j;
        Vb2[i] = f16b(V[(((size_t)l * NE + e) * DD + d) * RR + r]);
    }
    for (int i = tid; i < NL * 131072; i += nthr) {
        int l = i >> 17; int q = i & 131071;
        int dblk = q >> 12; int rem = q & 4095;
        int ks = rem >> 9; int ln = (rem >> 3) & 63; int j = rem & 7;
        int e = ks >> 1;
        int d = dblk * 16 + (ln & 15);
        int s = (ks & 1) * 32 + (ln >> 4) * 8 + j;
        Ub2[i] = f16b(U[(((size_t)l * NE + e) * DD + d) * RR + s]);
    }
    for (int i = tid; i < NL * 16384; i += nthr) {
        int l = i >> 14; int q = i & 16383;
        int e = q >> 12; int rem = q & 4095;
        int oc = rem >> 10; int kc = (rem >> 9) & 1;
        int ln = (rem >> 3) & 63; int j = rem & 7;
        int r = kc * 32 + (ln >> 4) * 8 + j;
        int s = oc * 16 + (ln & 15);
        Ct2[i] = f16b(C[(((size_t)l * NE + e) * RR + r) * RR + s]);
    }
}

// 16-slot XOR swizzle (R14-proven conflict-free); flips byte-addr bits 4..7 so
// 8B- and 16B-aligned accesses stay aligned.
#define XLB_ADDR(row, colbyte) (((row) * (DD * 2)) + ((colbyte) ^ (((row) & 15) << 4)))
#define VB_ADDR(row, colbyte)  (((row) * (NE * RR * 2)) + ((colbyte) ^ (((row) & 15) << 4)))

__global__ __launch_bounds__(THREADS, 4) void dcn_main(
    const float* __restrict__ x,
    const float* __restrict__ bias,
    const short* __restrict__ Vb2,
    const short* __restrict__ Ub2,
    const short* __restrict__ Ct2,
    float* __restrict__ out)
{
    __shared__ char xl_b[ROWS * DD * 2];        // 64 KiB fp16 xl carry tile (swizzled)
    __shared__ char x0_b[ROWS * DD * 2];        // 64 KiB fp16 x0 tile (swizzled)
    __shared__ char sbuf[ROWS * NE * RR * 2];   // 32 KiB shared v/cv tile (swizzled)

    const int t   = threadIdx.x;
    const int w   = t >> 6;          // wave 0..15
    const int ln  = t & 63;
    const int l15 = ln & 15;
    const int kg  = ln >> 4;         // k-group 0..3
    const int row_base = blockIdx.x * ROWS;

    // ---- preamble: x (fp32, coalesced float4) -> fp16 xl_b AND x0_b ----
    #pragma unroll
    for (int q = 0; q < 8; ++q) {
        int p   = t + q * THREADS;
        int row = p >> 7;                 // 128 float4 per row
        int d4  = (p & 127) << 2;
        const float4 v4 = *(const float4*)(x + (size_t)(row_base + row) * DD + d4);
        short4 pk;
        pk.x = f16b(v4.x); pk.y = f16b(v4.y); pk.z = f16b(v4.z); pk.w = f16b(v4.w);
        *(short4*)(xl_b + XLB_ADDR(row, d4 * 2)) = pk;
        *(short4*)(x0_b + XLB_ADDR(row, d4 * 2)) = pk;
    }
    __syncthreads();

    const int e2 = w >> 2;           // GEMM2 expert for this wave (4 waves/expert)
    const int q2 = w & 3;            // GEMM2 16-col quarter within expert

    #pragma unroll
    for (int layer = 0; layer < NL; ++layer) {
        const short* Vl = Vb2 + layer * 131072;
        const short* Ul = Ub2 + layer * 131072;
        const short* Cl = Ct2 + layer * 16384;
        const float* bl = bias + layer * DD;

        // ---- GEMM1 (swapped): v^T = V-frag * xl^T; wave owns v-cols [w*16,+16) ----
        // acc1[nt]: lane holds v-cols w*16+kg*4+{0..3}, batch row l15+16*nt.
        f32x4 acc1[4];
        #pragma unroll
        for (int nt = 0; nt < 4; ++nt) { f32x4 z = {0.f, 0.f, 0.f, 0.f}; acc1[nt] = z; }

        #pragma unroll 4
        for (int ks = 0; ks < 16; ++ks) {
            const int d0 = ks * 32 + kg * 8;
            f16x8 a = *(const f16x8*)(Vl + ((w * 16 + ks) << 9) + ln * 8);   // weights = A
            #pragma unroll
            for (int nt = 0; nt < 4; ++nt) {
                f16x8 b = *(const f16x8*)(xl_b + XLB_ADDR(l15 + 16 * nt, d0 * 2));
                acc1[nt] = MFMA(a, b, acc1[nt]);
            }
        }
        // v-store: 4 consecutive v-cols per lane -> one short4 (b64) per nt
        #pragma unroll
        for (int nt = 0; nt < 4; ++nt) {
            short4 pk;
            pk.x = f16b(ftanh(acc1[nt][0]));
            pk.y = f16b(ftanh(acc1[nt][1]));
            pk.z = f16b(ftanh(acc1[nt][2]));
            pk.w = f16b(ftanh(acc1[nt][3]));
            *(short4*)(sbuf + VB_ADDR(l15 + 16 * nt, (w * 16 + kg * 4) * 2)) = pk;
        }
        // GEMM2's tiny C a-frags (L2-hot) before the barrier
        f16x8 pfc0 = *(const f16x8*)(Cl + ((e2 * 8 + q2 * 2 + 0) << 9) + ln * 8);
        f16x8 pfc1 = *(const f16x8*)(Cl + ((e2 * 8 + q2 * 2 + 1) << 9) + ln * 8);
        __syncthreads();   // v visible

        // ---- GEMM2 (swapped): cv^T = C-frag * v^T; wave owns s-cols q2*16+ ----
        f32x4 acc2[4];
        #pragma unroll
        for (int nt = 0; nt < 4; ++nt) { f32x4 z = {0.f, 0.f, 0.f, 0.f}; acc2[nt] = z; }

        #pragma unroll
        for (int kc = 0; kc < 2; ++kc) {
            const int vcol = e2 * 64 + kc * 32 + kg * 8;
            f16x8 a = kc ? pfc1 : pfc0;
            #pragma unroll
            for (int nt = 0; nt < 4; ++nt) {
                f16x8 b = *(const f16x8*)(sbuf + VB_ADDR(l15 + 16 * nt, vcol * 2));
                acc2[nt] = MFMA(a, b, acc2[nt]);
            }
        }
        float cvv[4][4];
        #pragma unroll
        for (int nt = 0; nt < 4; ++nt)
          #pragma unroll
          for (int r = 0; r < 4; ++r) cvv[nt][r] = ftanh(acc2[nt][r]);
        __syncthreads();   // all v-reads done before cv overwrites sbuf
        #pragma unroll
        for (int nt = 0; nt < 4; ++nt) {
            short4 pk;
            pk.x = f16b(cvv[nt][0]); pk.y = f16b(cvv[nt][1]);
            pk.z = f16b(cvv[nt][2]); pk.w = f16b(cvv[nt][3]);
            *(short4*)(sbuf + VB_ADDR(l15 + 16 * nt, (e2 * 64 + q2 * 16 + kg * 4) * 2)) = pk;
        }
        __syncthreads();   // cv visible

        // ---- GEMM3 (swapped), two 16-d-col halves, fused vectorized epilogue ----
        #pragma unroll
        for (int h = 0; h < 2; ++h) {
            f32x4 acc3[4];
            #pragma unroll
            for (int nt = 0; nt < 4; ++nt) { f32x4 z = {0.f, 0.f, 0.f, 0.f}; acc3[nt] = z; }

            #pragma unroll 4
            for (int ks = 0; ks < 8; ++ks) {
                const int k0 = ks * 32 + kg * 8;
                f16x8 a = *(const f16x8*)(Ul + (((w * 2 + h) * 8 + ks) << 9) + ln * 8);
                #pragma unroll
                for (int nt = 0; nt < 4; ++nt) {
                    f16x8 b = *(const f16x8*)(sbuf + VB_ADDR(l15 + 16 * nt, k0 * 2));
                    acc3[nt] = MFMA(a, b, acc3[nt]);
                }
            }
            // epilogue: lane holds d-cols d0+{0..3} for batch row l15+16nt.
            // xl' = x0*(ucv + 4*bias) + xl_old  -- all b64 LDS ops + one float4 bias.
            const int d0 = w * 32 + h * 16 + kg * 4;
            const float4 bv4 = *(const float4*)(bl + d0);
            #pragma unroll
            for (int nt = 0; nt < 4; ++nt) {
                const int brow = l15 + 16 * nt;
                short4 xo = *(const short4*)(xl_b + XLB_ADDR(brow, d0 * 2));
                short4 x0 = *(const short4*)(x0_b + XLB_ADDR(brow, d0 * 2));
                short4 nw;
                nw.x = f16b(f16tof(x0.x) * (acc3[nt][0] + 4.0f * bv4.x) + f16tof(xo.x));
                nw.y = f16b(f16tof(x0.y) * (acc3[nt][1] + 4.0f * bv4.y) + f16tof(xo.y));
                nw.z = f16b(f16tof(x0.z) * (acc3[nt][2] + 4.0f * bv4.z) + f16tof(xo.z));
                nw.w = f16b(f16tof(x0.w) * (acc3[nt][3] + 4.0f * bv4.w) + f16tof(xo.w));
                *(short4*)(xl_b + XLB_ADDR(brow, d0 * 2)) = nw;
            }
        }
        __syncthreads();   // xl' visible to next GEMM1 / final copy
    }

    // ---- final: coalesced float4 store of xl_b (fp16 -> fp32) ----
    #pragma unroll
    for (int q = 0; q < 8; ++q) {
        int p   = t + q * THREADS;
        int row = p >> 7;
        int d4  = (p & 127) << 2;
        short4 pk = *(const short4*)(xl_b + XLB_ADDR(row, d4 * 2));
        float4 v4;
        v4.x = f16tof(pk.x); v4.y = f16tof(pk.y); v4.z = f16tof(pk.z); v4.w = f16tof(pk.w);
        *(float4*)(out + (size_t)(row_base + row) * DD + d4) = v4;
    }
}

extern "C" void kernel_launch(void* const* d_in, const int* in_sizes, int n_in,
                              void* d_out, int out_size, void* d_ws, size_t ws_size,
                              hipStream_t stream) {
    const float* x    = (const float*)d_in[0];
    const float* U    = (const float*)d_in[1];
    const float* V    = (const float*)d_in[2];
    const float* C    = (const float*)d_in[3];
    // d_in[4] = G : unused (gate == 1 exactly)
    const float* bias = (const float*)d_in[5];
    float* out = (float*)d_out;

    short* Vb2 = (short*)d_ws;                 // 786432 B
    short* Ub2 = Vb2 + NL * 131072;            // 786432 B
    short* Ct2 = Ub2 + NL * 131072;            // 98304 B  (total ~1.6 MiB)

    prep_kernel<<<dim3(256), dim3(256), 0, stream>>>(U, V, C, Vb2, Ub2, Ct2);
    dcn_main<<<dim3(16384 / ROWS), dim3(THREADS), 0, stream>>>(x, bias, Vb2, Ub2, Ct2, out);
}